// Round 6
// baseline (537.711 us; speedup 1.0000x reference)
//
#include <hip/hip_runtime.h>
#include <math.h>

// Problem constants
#define B_    8
#define L_    512
#define K_    16
#define E_    32
#define NH_   64
#define WOFF_ 1

// Workspace layout (floats):
//   qmat  [B][L][32]   @ 0        (131072)
//   kmatT [B][32][L]   @ 131072   (131072)
//   att   [B][L][64]   @ 262144   (262144)
//   gi    [B][L][192]  @ 524288   (786432)

// ---------------------------------------------------------------------------
// Kernel 1: key_emb -> q, k projections. One thread per (b,l).
// ---------------------------------------------------------------------------
__global__ __launch_bounds__(256) void k_embed(
    const float* __restrict__ ts, const float* __restrict__ Wl,
    const float* __restrict__ bl, const float* __restrict__ Wp,
    const float* __restrict__ bp, const float* __restrict__ Wq,
    const float* __restrict__ bq, const float* __restrict__ Wk,
    const float* __restrict__ bk,
    float* __restrict__ qmat, float* __restrict__ kmatT)
{
    __shared__ float WqL[1024], WkL[1024];
    __shared__ float bqL[32], bkL[32], WpL[31], bpL[31];
    __shared__ float wl0, bl0;
    const int tid = threadIdx.x;

    {
        float4 v = ((const float4*)Wq)[tid];
        ((float4*)WqL)[tid] = v;
        float4 u = ((const float4*)Wk)[tid];
        ((float4*)WkL)[tid] = u;
    }
    if (tid < 32) { bqL[tid] = bq[tid]; bkL[tid] = bk[tid]; }
    if (tid < 31) { WpL[tid] = Wp[tid]; bpL[tid] = bp[tid]; }
    if (tid == 0) { wl0 = Wl[0]; bl0 = bl[0]; }
    __syncthreads();

    const int p = blockIdx.x * 256 + tid;      // 0..4095
    const float t = ts[p];
    float e[32];
    e[0] = t * wl0 + bl0;
    #pragma unroll
    for (int j = 1; j < 32; ++j) e[j] = sinf(t * WpL[j - 1] + bpL[j - 1]);

    const int b = p >> 9, l = p & 511;
    float4* qm4 = (float4*)(qmat + (size_t)p * 32);
    float*  kT  = kmatT + (size_t)b * 32 * 512 + l;

    for (int dq = 0; dq < 8; ++dq) {
        float q0 = bqL[4*dq+0], q1 = bqL[4*dq+1], q2 = bqL[4*dq+2], q3 = bqL[4*dq+3];
        float k0 = bkL[4*dq+0], k1 = bkL[4*dq+1], k2 = bkL[4*dq+2], k3 = bkL[4*dq+3];
        const float* wq = &WqL[(4*dq) * 32];
        const float* wk = &WkL[(4*dq) * 32];
        #pragma unroll
        for (int j = 0; j < 32; ++j) {
            const float ej = e[j];
            q0 = fmaf(wq[j],      ej, q0);
            q1 = fmaf(wq[32 + j], ej, q1);
            q2 = fmaf(wq[64 + j], ej, q2);
            q3 = fmaf(wq[96 + j], ej, q3);
            k0 = fmaf(wk[j],      ej, k0);
            k1 = fmaf(wk[32 + j], ej, k1);
            k2 = fmaf(wk[64 + j], ej, k2);
            k3 = fmaf(wk[96 + j], ej, k3);
        }
        qm4[dq] = make_float4(q0, q1, q2, q3);
        kT[(4*dq + 0) * 512] = k0;
        kT[(4*dq + 1) * 512] = k1;
        kT[(4*dq + 2) * 512] = k2;
        kT[(4*dq + 3) * 512] = k3;
    }
}

// ---------------------------------------------------------------------------
// Kernel 2: per-(b,q) attention -> att_out.  grid (32 qb, 8 b), 256 thr.
// ---------------------------------------------------------------------------
__global__ __launch_bounds__(256) void k_attn(
    const float* __restrict__ qmat, const float* __restrict__ kmatT,
    const float* __restrict__ val,  const int*   __restrict__ mark,
    const float* __restrict__ npm,  const float* __restrict__ Wo,
    const float* __restrict__ bo,   float* __restrict__ att)
{
    __shared__ float srow[4 * 512];   // per-wave score row
    __shared__ int   cc[512];         // category (-1 if padded)
    __shared__ float vv[512];         // values
    const int tid = threadIdx.x;
    const int qb  = blockIdx.x;       // 0..31
    const int b   = blockIdx.y;       // 0..7

    for (int k = tid; k < 512; k += 256) {
        const int   m  = mark[b * 512 + k];
        const float np = npm[b * 512 + k];
        cc[k] = (np > 0.0f) ? (m - 1) : -1;
        vv[k] = val[b * 512 + k];
    }
    __syncthreads();

    const int w = tid >> 6, lane = tid & 63;
    const float* kTb = kmatT + (size_t)b * 32 * 512;

    for (int iq = 0; iq < 4; ++iq) {
        const int q = qb * 16 + w * 4 + iq;

        float qr[32];
        const float4* qm4 = (const float4*)(qmat + (size_t)(b * 512 + q) * 32);
        #pragma unroll
        for (int j4 = 0; j4 < 8; ++j4) {
            float4 v = qm4[j4];
            qr[4*j4+0] = v.x; qr[4*j4+1] = v.y; qr[4*j4+2] = v.z; qr[4*j4+3] = v.w;
        }

        float acc[8];
        #pragma unroll
        for (int m = 0; m < 8; ++m) acc[m] = 0.0f;
        #pragma unroll 4
        for (int j = 0; j < 32; ++j) {
            const float* row = kTb + j * 512 + lane;
            const float  qj  = qr[j];
            #pragma unroll
            for (int m = 0; m < 8; ++m) acc[m] = fmaf(qj, row[m * 64], acc[m]);
        }
        #pragma unroll
        for (int m = 0; m < 8; ++m)
            srow[w * 512 + m * 64 + lane] = acc[m] * 0.17677669529663687f;
        __syncthreads();

        const int c = lane & 15, s = lane >> 4;
        float mx = -1e30f, Z = 0.0f, X = 0.0f;
        const int base = s * 128;
        for (int t = 0; t < 128; ++t) {
            const int k = base + ((t + s) & 127);
            if (cc[k] == c) {
                const float l  = (k <= q + WOFF_) ? srow[w * 512 + k] : 0.0f;
                const float mn = fmaxf(mx, l);
                const float e1 = __expf(l - mn);
                const float sc = __expf(mx - mn);
                Z = Z * sc + e1;
                X = X * sc + e1 * vv[k];
                mx = mn;
            }
        }
        #pragma unroll
        for (int off = 16; off <= 32; off <<= 1) {
            const float mo = __shfl_xor(mx, off);
            const float Zo = __shfl_xor(Z, off);
            const float Xo = __shfl_xor(X, off);
            const float mn = fmaxf(mx, mo);
            const float a0 = __expf(mx - mn);
            const float a1 = __expf(mo - mn);
            Z = Z * a0 + Zo * a1;
            X = X * a0 + Xo * a1;
            mx = mn;
        }
        const float x = (Z > 0.0f) ? X / Z : 0.0f;

        float xs[16];
        #pragma unroll
        for (int c2 = 0; c2 < 16; ++c2) xs[c2] = __shfl(x, c2);

        const float4* wo4 = (const float4*)(Wo + lane * 16);
        float a = bo[lane];
        #pragma unroll
        for (int c4 = 0; c4 < 4; ++c4) {
            float4 v = wo4[c4];
            a += xs[4*c4+0] * v.x + xs[4*c4+1] * v.y + xs[4*c4+2] * v.z + xs[4*c4+3] * v.w;
        }
        att[(size_t)(b * 512 + q) * 64 + lane] = a;
        __syncthreads();
    }
}

// ---------------------------------------------------------------------------
// Kernel 3: gi = att @ W_ih^T + b_ih.  256 blocks x 16 rows each.
// ---------------------------------------------------------------------------
__global__ __launch_bounds__(256) void k_gi(
    const float* __restrict__ att, const float* __restrict__ Wih,
    const float* __restrict__ bih, float* __restrict__ gi)
{
    __shared__ float WL[192 * 65];
    __shared__ float attL[16 * 64];
    __shared__ float bL[192];
    const int tid = threadIdx.x;

    for (int idx = tid; idx < 3072; idx += 256) {
        float4 v = ((const float4*)Wih)[idx];
        const int g = idx >> 4, jq = idx & 15;
        float* dst = &WL[g * 65 + jq * 4];
        dst[0] = v.x; dst[1] = v.y; dst[2] = v.z; dst[3] = v.w;
    }
    if (tid < 192) bL[tid] = bih[tid];
    {
        float4 v = ((const float4*)att)[blockIdx.x * 256 + tid];
        ((float4*)attL)[tid] = v;
    }
    __syncthreads();

    const size_t out0 = (size_t)blockIdx.x * 16 * 192;
    for (int pp = 0; pp < 12; ++pp) {
        const int p = tid + 256 * pp;
        const int r = p / 192, g = p - r * 192;
        float a0 = bL[g], a1 = 0.f, a2 = 0.f, a3 = 0.f;
        const float* wrow = &WL[g * 65];
        const float* arow = &attL[r * 64];
        #pragma unroll
        for (int j = 0; j < 64; j += 4) {
            a0 = fmaf(arow[j + 0], wrow[j + 0], a0);
            a1 = fmaf(arow[j + 1], wrow[j + 1], a1);
            a2 = fmaf(arow[j + 2], wrow[j + 2], a2);
            a3 = fmaf(arow[j + 3], wrow[j + 3], a3);
        }
        gi[out0 + p] = (a0 + a1) + (a2 + a3);
    }
}

// ---------------------------------------------------------------------------
// Kernel 4: sequential GRU — one wave/batch, FULL explicit-register asm body.
//
// R2-R5 evidence: HIP register allocator always homes the 192 persistent
// weight floats in AGPRs (VGPR_Count stuck at 104-132), paying ~192
// v_accvgpr_read per step. Constraint-level asm can't override homes.
// Fix: entire loop in one asm block with explicit registers:
//   v0 h | v1-v3 gi prefetch | v4-v6 acc | v7-v12 act temps |
//   v13-v15 bias | v16/v17 clamp | v20-v29 ptrs | v32-v223 weights
// Broadcast h_j: v_readlane into s10/s11 alternating, rotated so each
// SGPR write has >=4 insts before first VALU use (hazard-safe).
// Prefetch: 3 loads issued at top, s_waitcnt vmcnt(1) (store stays in
// flight). Last-iter prefetch address clamped via s_cselect (no OOB read).
// ---------------------------------------------------------------------------
#define LD4(D0, D3, B0, B1, OFF) \
  "global_load_dwordx4 v[" #D0 ":" #D3 "], v[" #B0 ":" #B1 "], off offset:" #OFF "\n\t"

#define MV(S, JW, JZ, JN, NL) \
  "v_fmac_f32 v4, " S ", v" #JW "\n\t" \
  "v_fmac_f32 v5, " S ", v" #JZ "\n\t" \
  "v_fmac_f32 v6, " S ", v" #JN "\n\t" \
  "v_readlane_b32 " S ", v0, " #NL "\n\t"

#define MVE(S, JW, JZ, JN) \
  "v_fmac_f32 v4, " S ", v" #JW "\n\t" \
  "v_fmac_f32 v5, " S ", v" #JZ "\n\t" \
  "v_fmac_f32 v6, " S ", v" #JN "\n\t"

__global__
__attribute__((amdgpu_flat_work_group_size(64, 64)))
void k_gru(
    const float* __restrict__ gi, const float* __restrict__ Whh,
    const float* __restrict__ bhh, float* __restrict__ out)
{
    const int lane = threadIdx.x;     // 0..63
    const int b    = blockIdx.x;      // 0..7

    const float br = bhh[lane];
    const float bz = bhh[lane + 64];
    const float bn = bhh[lane + 128];

    const float* gib  = gi  + (size_t)b * 512 * 192;
    float*       outb = out + (size_t)b * 512 * 64;

    asm volatile(
        // ---- setup: weight base addresses (Whh + lane*256B; +16KB; +32KB)
        "v_lshlrev_b32 v30, 8, %[lane]\n\t"
        "v_mov_b32 v25, %[whi]\n\t"
        "v_add_co_u32 v24, vcc, %[wlo], v30\n\t"
        "v_addc_co_u32 v25, vcc, v25, 0, vcc\n\t"
        "v_add_co_u32 v26, vcc, 0x4000, v24\n\t"
        "v_mov_b32 v27, v25\n\t"
        "v_addc_co_u32 v27, vcc, v27, 0, vcc\n\t"
        "v_add_co_u32 v28, vcc, 0x8000, v24\n\t"
        "v_mov_b32 v29, v25\n\t"
        "v_addc_co_u32 v29, vcc, v29, 0, vcc\n\t"
        // ---- stage W_hh rows: wr->v32..95, wz->v96..159, wn->v160..223
        LD4( 32, 35,24,25,  0) LD4( 36, 39,24,25, 16) LD4( 40, 43,24,25, 32) LD4( 44, 47,24,25, 48)
        LD4( 48, 51,24,25, 64) LD4( 52, 55,24,25, 80) LD4( 56, 59,24,25, 96) LD4( 60, 63,24,25,112)
        LD4( 64, 67,24,25,128) LD4( 68, 71,24,25,144) LD4( 72, 75,24,25,160) LD4( 76, 79,24,25,176)
        LD4( 80, 83,24,25,192) LD4( 84, 87,24,25,208) LD4( 88, 91,24,25,224) LD4( 92, 95,24,25,240)
        LD4( 96, 99,26,27,  0) LD4(100,103,26,27, 16) LD4(104,107,26,27, 32) LD4(108,111,26,27, 48)
        LD4(112,115,26,27, 64) LD4(116,119,26,27, 80) LD4(120,123,26,27, 96) LD4(124,127,26,27,112)
        LD4(128,131,26,27,128) LD4(132,135,26,27,144) LD4(136,139,26,27,160) LD4(140,143,26,27,176)
        LD4(144,147,26,27,192) LD4(148,151,26,27,208) LD4(152,155,26,27,224) LD4(156,159,26,27,240)
        LD4(160,163,28,29,  0) LD4(164,167,28,29, 16) LD4(168,171,28,29, 32) LD4(172,175,28,29, 48)
        LD4(176,179,28,29, 64) LD4(180,183,28,29, 80) LD4(184,187,28,29, 96) LD4(188,191,28,29,112)
        LD4(192,195,28,29,128) LD4(196,199,28,29,144) LD4(200,203,28,29,160) LD4(204,207,28,29,176)
        LD4(208,211,28,29,192) LD4(212,215,28,29,208) LD4(216,219,28,29,224) LD4(220,223,28,29,240)
        // ---- gi / out pointers (+ lane*4)
        "v_lshlrev_b32 v30, 2, %[lane]\n\t"
        "v_mov_b32 v21, %[ghi]\n\t"
        "v_add_co_u32 v20, vcc, %[glo], v30\n\t"
        "v_addc_co_u32 v21, vcc, v21, 0, vcc\n\t"
        "v_mov_b32 v23, %[ohi]\n\t"
        "v_add_co_u32 v22, vcc, %[olo], v30\n\t"
        "v_addc_co_u32 v23, vcc, v23, 0, vcc\n\t"
        // ---- constants / state
        "v_mov_b32 v13, %[br]\n\t"
        "v_mov_b32 v14, %[bz]\n\t"
        "v_mov_b32 v15, %[bn]\n\t"
        "v_mov_b32 v16, 0x41700000\n\t"   // +15.0
        "v_mov_b32 v17, 0xc1700000\n\t"   // -15.0
        "v_mov_b32 v0, 0\n\t"             // h = 0
        // ---- preload gi[0]
        "global_load_dword v1, v[20:21], off\n\t"
        "global_load_dword v2, v[20:21], off offset:256\n\t"
        "global_load_dword v3, v[20:21], off offset:512\n\t"
        "s_mov_b32 s31, 0x200\n\t"
        "s_waitcnt vmcnt(0)\n\t"
        // ================= main loop: 512 steps =================
        "L_gru_%=:\n\t"
        "s_waitcnt vmcnt(1)\n\t"          // 3 gi loads done; store may fly
        "v_readlane_b32 s10, v0, 0\n\t"
        "v_readlane_b32 s11, v0, 1\n\t"
        "v_add_f32 v4, v13, v1\n\t"       // ar = br + gr
        "v_add_f32 v5, v14, v2\n\t"       // az = bz + gz
        "v_mov_b32 v7, v3\n\t"            // gn_cur
        "v_mov_b32 v6, v15\n\t"           // hn acc = bn
        // advance gi ptr (clamped on last iter -> no OOB prefetch)
        "s_cmp_gt_u32 s31, 1\n\t"
        "s_cselect_b32 s12, 0x300, 0\n\t"
        "v_add_co_u32 v20, vcc, s12, v20\n\t"
        "v_addc_co_u32 v21, vcc, v21, 0, vcc\n\t"
        "global_load_dword v1, v[20:21], off\n\t"
        "global_load_dword v2, v[20:21], off offset:256\n\t"
        "global_load_dword v3, v[20:21], off offset:512\n\t"
        // ---- matvec: 64 broadcast groups, s10/s11 rotated
        MV("s10", 32, 96,160, 2) MV("s11", 33, 97,161, 3)
        MV("s10", 34, 98,162, 4) MV("s11", 35, 99,163, 5)
        MV("s10", 36,100,164, 6) MV("s11", 37,101,165, 7)
        MV("s10", 38,102,166, 8) MV("s11", 39,103,167, 9)
        MV("s10", 40,104,168,10) MV("s11", 41,105,169,11)
        MV("s10", 42,106,170,12) MV("s11", 43,107,171,13)
        MV("s10", 44,108,172,14) MV("s11", 45,109,173,15)
        MV("s10", 46,110,174,16) MV("s11", 47,111,175,17)
        MV("s10", 48,112,176,18) MV("s11", 49,113,177,19)
        MV("s10", 50,114,178,20) MV("s11", 51,115,179,21)
        MV("s10", 52,116,180,22) MV("s11", 53,117,181,23)
        MV("s10", 54,118,182,24) MV("s11", 55,119,183,25)
        MV("s10", 56,120,184,26) MV("s11", 57,121,185,27)
        MV("s10", 58,122,186,28) MV("s11", 59,123,187,29)
        MV("s10", 60,124,188,30) MV("s11", 61,125,189,31)
        MV("s10", 62,126,190,32) MV("s11", 63,127,191,33)
        MV("s10", 64,128,192,34) MV("s11", 65,129,193,35)
        MV("s10", 66,130,194,36) MV("s11", 67,131,195,37)
        MV("s10", 68,132,196,38) MV("s11", 69,133,197,39)
        MV("s10", 70,134,198,40) MV("s11", 71,135,199,41)
        MV("s10", 72,136,200,42) MV("s11", 73,137,201,43)
        MV("s10", 74,138,202,44) MV("s11", 75,139,203,45)
        MV("s10", 76,140,204,46) MV("s11", 77,141,205,47)
        MV("s10", 78,142,206,48) MV("s11", 79,143,207,49)
        MV("s10", 80,144,208,50) MV("s11", 81,145,209,51)
        MV("s10", 82,146,210,52) MV("s11", 83,147,211,53)
        MV("s10", 84,148,212,54) MV("s11", 85,149,213,55)
        MV("s10", 86,150,214,56) MV("s11", 87,151,215,57)
        MV("s10", 88,152,216,58) MV("s11", 89,153,217,59)
        MV("s10", 90,154,218,60) MV("s11", 91,155,219,61)
        MV("s10", 92,156,220,62) MV("s11", 93,157,221,63)
        MVE("s10", 94,158,222)   MVE("s11", 95,159,223)
        // ---- activations: r=sig(v4), z=sig(v5), n=tanh(v7 + r*v6)
        "v_mul_f32 v8, 0xbfb8aa3b, v4\n\t"    // -ar*log2e
        "v_mul_f32 v9, 0xbfb8aa3b, v5\n\t"
        "v_exp_f32 v8, v8\n\t"
        "v_exp_f32 v9, v9\n\t"
        "v_add_f32 v8, 1.0, v8\n\t"
        "v_add_f32 v9, 1.0, v9\n\t"
        "v_rcp_f32 v8, v8\n\t"                // r
        "v_rcp_f32 v9, v9\n\t"                // z
        "v_fmac_f32 v7, v8, v6\n\t"           // npre = gn + r*hn
        "v_med3_f32 v7, v7, v17, v16\n\t"     // clamp +-15
        "v_mul_f32 v10, 0x4038aa3b, v7\n\t"   // 2*log2e*npre
        "v_exp_f32 v10, v10\n\t"              // e2 = e^(2 npre)
        "s_nop 0\n\t"
        "v_add_f32 v11, 1.0, v10\n\t"
        "v_add_f32 v10, -1.0, v10\n\t"
        "v_rcp_f32 v11, v11\n\t"
        "s_nop 0\n\t"
        "v_mul_f32 v10, v10, v11\n\t"         // n = (e2-1)/(e2+1)
        "v_sub_f32 v12, v0, v10\n\t"          // h - n
        "v_fma_f32 v0, v9, v12, v10\n\t"      // h = z*(h-n)+n
        "global_store_dword v[22:23], v0, off\n\t"
        "v_add_co_u32 v22, vcc, 0x100, v22\n\t"
        "v_addc_co_u32 v23, vcc, v23, 0, vcc\n\t"
        "s_sub_u32 s31, s31, 1\n\t"
        "s_cmp_lg_u32 s31, 0\n\t"
        "s_cbranch_scc1 L_gru_%=\n\t"
        "s_waitcnt vmcnt(0)\n\t"
        :
        : [lane]"v"(lane), [br]"v"(br), [bz]"v"(bz), [bn]"v"(bn),
          [glo]"s"((unsigned)(unsigned long long)gib),
          [ghi]"s"((unsigned)((unsigned long long)gib >> 32)),
          [olo]"s"((unsigned)(unsigned long long)outb),
          [ohi]"s"((unsigned)((unsigned long long)outb >> 32)),
          [wlo]"s"((unsigned)(unsigned long long)Whh),
          [whi]"s"((unsigned)((unsigned long long)Whh >> 32))
        : "memory", "vcc", "scc", "s10", "s11", "s12", "s31",
          "v0","v1","v2","v3","v4","v5","v6","v7","v8","v9","v10","v11","v12","v13","v14","v15",
          "v16","v17","v18","v19","v20","v21","v22","v23","v24","v25","v26","v27","v28","v29","v30",
          "v32","v33","v34","v35","v36","v37","v38","v39","v40","v41","v42","v43","v44","v45","v46","v47",
          "v48","v49","v50","v51","v52","v53","v54","v55","v56","v57","v58","v59","v60","v61","v62","v63",
          "v64","v65","v66","v67","v68","v69","v70","v71","v72","v73","v74","v75","v76","v77","v78","v79",
          "v80","v81","v82","v83","v84","v85","v86","v87","v88","v89","v90","v91","v92","v93","v94","v95",
          "v96","v97","v98","v99","v100","v101","v102","v103","v104","v105","v106","v107","v108","v109","v110","v111",
          "v112","v113","v114","v115","v116","v117","v118","v119","v120","v121","v122","v123","v124","v125","v126","v127",
          "v128","v129","v130","v131","v132","v133","v134","v135","v136","v137","v138","v139","v140","v141","v142","v143",
          "v144","v145","v146","v147","v148","v149","v150","v151","v152","v153","v154","v155","v156","v157","v158","v159",
          "v160","v161","v162","v163","v164","v165","v166","v167","v168","v169","v170","v171","v172","v173","v174","v175",
          "v176","v177","v178","v179","v180","v181","v182","v183","v184","v185","v186","v187","v188","v189","v190","v191",
          "v192","v193","v194","v195","v196","v197","v198","v199","v200","v201","v202","v203","v204","v205","v206","v207",
          "v208","v209","v210","v211","v212","v213","v214","v215","v216","v217","v218","v219","v220","v221","v222","v223"
    );
}

// ---------------------------------------------------------------------------
extern "C" void kernel_launch(void* const* d_in, const int* in_sizes, int n_in,
                              void* d_out, int out_size, void* d_ws, size_t ws_size,
                              hipStream_t stream)
{
    const float* ts   = (const float*)d_in[0];
    const float* val  = (const float*)d_in[1];
    const int*   mark = (const int*)  d_in[2];
    const float* npm  = (const float*)d_in[3];
    const float* Wl   = (const float*)d_in[4];
    const float* bl   = (const float*)d_in[5];
    const float* Wp   = (const float*)d_in[6];
    const float* bp   = (const float*)d_in[7];
    const float* Wq   = (const float*)d_in[8];
    const float* bq   = (const float*)d_in[9];
    const float* Wk   = (const float*)d_in[10];
    const float* bk   = (const float*)d_in[11];
    const float* Wo   = (const float*)d_in[12];
    const float* bo   = (const float*)d_in[13];
    const float* Wih  = (const float*)d_in[14];
    const float* Whh  = (const float*)d_in[15];
    const float* bih  = (const float*)d_in[16];
    const float* bhh  = (const float*)d_in[17];

    float* ws    = (float*)d_ws;
    float* qmat  = ws;                 // 131072
    float* kmatT = ws + 131072;        // 131072
    float* att   = ws + 262144;        // 262144
    float* gi    = ws + 524288;        // 786432
    float* out   = (float*)d_out;

    k_embed<<<16, 256, 0, stream>>>(ts, Wl, bl, Wp, bp, Wq, bq, Wk, bk, qmat, kmatT);
    k_attn<<<dim3(32, 8), 256, 0, stream>>>(qmat, kmatT, val, mark, npm, Wo, bo, att);
    k_gi<<<256, 256, 0, stream>>>(att, Wih, bih, gi);
    k_gru<<<8, 64, 0, stream>>>(gi, Whh, bhh, out);
}

// Round 7
// 493.199 us; speedup vs baseline: 1.0903x; 1.0903x over previous
//
#include <hip/hip_runtime.h>
#include <math.h>

// Problem constants
#define B_    8
#define L_    512
#define K_    16
#define E_    32
#define NH_   64
#define WOFF_ 1

// Workspace layout (floats):
//   qmat  [B][L][32]   @ 0        (131072)
//   kmatT [B][32][L]   @ 131072   (131072)
//   att   [B][L][64]   @ 262144   (262144)
//   gi    [B][L][192]  @ 524288   (786432)

// ---------------------------------------------------------------------------
// Kernel 1: key_emb -> q, k projections. One thread per (b,l).
// ---------------------------------------------------------------------------
__global__ __launch_bounds__(256) void k_embed(
    const float* __restrict__ ts, const float* __restrict__ Wl,
    const float* __restrict__ bl, const float* __restrict__ Wp,
    const float* __restrict__ bp, const float* __restrict__ Wq,
    const float* __restrict__ bq, const float* __restrict__ Wk,
    const float* __restrict__ bk,
    float* __restrict__ qmat, float* __restrict__ kmatT)
{
    __shared__ float WqL[1024], WkL[1024];
    __shared__ float bqL[32], bkL[32], WpL[31], bpL[31];
    __shared__ float wl0, bl0;
    const int tid = threadIdx.x;

    {
        float4 v = ((const float4*)Wq)[tid];
        ((float4*)WqL)[tid] = v;
        float4 u = ((const float4*)Wk)[tid];
        ((float4*)WkL)[tid] = u;
    }
    if (tid < 32) { bqL[tid] = bq[tid]; bkL[tid] = bk[tid]; }
    if (tid < 31) { WpL[tid] = Wp[tid]; bpL[tid] = bp[tid]; }
    if (tid == 0) { wl0 = Wl[0]; bl0 = bl[0]; }
    __syncthreads();

    const int p = blockIdx.x * 256 + tid;      // 0..4095
    const float t = ts[p];
    float e[32];
    e[0] = t * wl0 + bl0;
    #pragma unroll
    for (int j = 1; j < 32; ++j) e[j] = sinf(t * WpL[j - 1] + bpL[j - 1]);

    const int b = p >> 9, l = p & 511;
    float4* qm4 = (float4*)(qmat + (size_t)p * 32);
    float*  kT  = kmatT + (size_t)b * 32 * 512 + l;

    for (int dq = 0; dq < 8; ++dq) {
        float q0 = bqL[4*dq+0], q1 = bqL[4*dq+1], q2 = bqL[4*dq+2], q3 = bqL[4*dq+3];
        float k0 = bkL[4*dq+0], k1 = bkL[4*dq+1], k2 = bkL[4*dq+2], k3 = bkL[4*dq+3];
        const float* wq = &WqL[(4*dq) * 32];
        const float* wk = &WkL[(4*dq) * 32];
        #pragma unroll
        for (int j = 0; j < 32; ++j) {
            const float ej = e[j];
            q0 = fmaf(wq[j],      ej, q0);
            q1 = fmaf(wq[32 + j], ej, q1);
            q2 = fmaf(wq[64 + j], ej, q2);
            q3 = fmaf(wq[96 + j], ej, q3);
            k0 = fmaf(wk[j],      ej, k0);
            k1 = fmaf(wk[32 + j], ej, k1);
            k2 = fmaf(wk[64 + j], ej, k2);
            k3 = fmaf(wk[96 + j], ej, k3);
        }
        qm4[dq] = make_float4(q0, q1, q2, q3);
        kT[(4*dq + 0) * 512] = k0;
        kT[(4*dq + 1) * 512] = k1;
        kT[(4*dq + 2) * 512] = k2;
        kT[(4*dq + 3) * 512] = k3;
    }
}

// ---------------------------------------------------------------------------
// Kernel 2: per-(b,q) attention -> att_out.  grid (32 qb, 8 b), 256 thr.
// ---------------------------------------------------------------------------
__global__ __launch_bounds__(256) void k_attn(
    const float* __restrict__ qmat, const float* __restrict__ kmatT,
    const float* __restrict__ val,  const int*   __restrict__ mark,
    const float* __restrict__ npm,  const float* __restrict__ Wo,
    const float* __restrict__ bo,   float* __restrict__ att)
{
    __shared__ float srow[4 * 512];   // per-wave score row
    __shared__ int   cc[512];         // category (-1 if padded)
    __shared__ float vv[512];         // values
    const int tid = threadIdx.x;
    const int qb  = blockIdx.x;       // 0..31
    const int b   = blockIdx.y;       // 0..7

    for (int k = tid; k < 512; k += 256) {
        const int   m  = mark[b * 512 + k];
        const float np = npm[b * 512 + k];
        cc[k] = (np > 0.0f) ? (m - 1) : -1;
        vv[k] = val[b * 512 + k];
    }
    __syncthreads();

    const int w = tid >> 6, lane = tid & 63;
    const float* kTb = kmatT + (size_t)b * 32 * 512;

    for (int iq = 0; iq < 4; ++iq) {
        const int q = qb * 16 + w * 4 + iq;

        float qr[32];
        const float4* qm4 = (const float4*)(qmat + (size_t)(b * 512 + q) * 32);
        #pragma unroll
        for (int j4 = 0; j4 < 8; ++j4) {
            float4 v = qm4[j4];
            qr[4*j4+0] = v.x; qr[4*j4+1] = v.y; qr[4*j4+2] = v.z; qr[4*j4+3] = v.w;
        }

        float acc[8];
        #pragma unroll
        for (int m = 0; m < 8; ++m) acc[m] = 0.0f;
        #pragma unroll 4
        for (int j = 0; j < 32; ++j) {
            const float* row = kTb + j * 512 + lane;
            const float  qj  = qr[j];
            #pragma unroll
            for (int m = 0; m < 8; ++m) acc[m] = fmaf(qj, row[m * 64], acc[m]);
        }
        #pragma unroll
        for (int m = 0; m < 8; ++m)
            srow[w * 512 + m * 64 + lane] = acc[m] * 0.17677669529663687f;
        __syncthreads();

        const int c = lane & 15, s = lane >> 4;
        float mx = -1e30f, Z = 0.0f, X = 0.0f;
        const int base = s * 128;
        for (int t = 0; t < 128; ++t) {
            const int k = base + ((t + s) & 127);
            if (cc[k] == c) {
                const float l  = (k <= q + WOFF_) ? srow[w * 512 + k] : 0.0f;
                const float mn = fmaxf(mx, l);
                const float e1 = __expf(l - mn);
                const float sc = __expf(mx - mn);
                Z = Z * sc + e1;
                X = X * sc + e1 * vv[k];
                mx = mn;
            }
        }
        #pragma unroll
        for (int off = 16; off <= 32; off <<= 1) {
            const float mo = __shfl_xor(mx, off);
            const float Zo = __shfl_xor(Z, off);
            const float Xo = __shfl_xor(X, off);
            const float mn = fmaxf(mx, mo);
            const float a0 = __expf(mx - mn);
            const float a1 = __expf(mo - mn);
            Z = Z * a0 + Zo * a1;
            X = X * a0 + Xo * a1;
            mx = mn;
        }
        const float x = (Z > 0.0f) ? X / Z : 0.0f;

        float xs[16];
        #pragma unroll
        for (int c2 = 0; c2 < 16; ++c2) xs[c2] = __shfl(x, c2);

        const float4* wo4 = (const float4*)(Wo + lane * 16);
        float a = bo[lane];
        #pragma unroll
        for (int c4 = 0; c4 < 4; ++c4) {
            float4 v = wo4[c4];
            a += xs[4*c4+0] * v.x + xs[4*c4+1] * v.y + xs[4*c4+2] * v.z + xs[4*c4+3] * v.w;
        }
        att[(size_t)(b * 512 + q) * 64 + lane] = a;
        __syncthreads();
    }
}

// ---------------------------------------------------------------------------
// Kernel 3: gi = att @ W_ih^T + b_ih.  256 blocks x 16 rows each.
// ---------------------------------------------------------------------------
__global__ __launch_bounds__(256) void k_gi(
    const float* __restrict__ att, const float* __restrict__ Wih,
    const float* __restrict__ bih, float* __restrict__ gi)
{
    __shared__ float WL[192 * 65];
    __shared__ float attL[16 * 64];
    __shared__ float bL[192];
    const int tid = threadIdx.x;

    for (int idx = tid; idx < 3072; idx += 256) {
        float4 v = ((const float4*)Wih)[idx];
        const int g = idx >> 4, jq = idx & 15;
        float* dst = &WL[g * 65 + jq * 4];
        dst[0] = v.x; dst[1] = v.y; dst[2] = v.z; dst[3] = v.w;
    }
    if (tid < 192) bL[tid] = bih[tid];
    {
        float4 v = ((const float4*)att)[blockIdx.x * 256 + tid];
        ((float4*)attL)[tid] = v;
    }
    __syncthreads();

    const size_t out0 = (size_t)blockIdx.x * 16 * 192;
    for (int pp = 0; pp < 12; ++pp) {
        const int p = tid + 256 * pp;
        const int r = p / 192, g = p - r * 192;
        float a0 = bL[g], a1 = 0.f, a2 = 0.f, a3 = 0.f;
        const float* wrow = &WL[g * 65];
        const float* arow = &attL[r * 64];
        #pragma unroll
        for (int j = 0; j < 64; j += 4) {
            a0 = fmaf(arow[j + 0], wrow[j + 0], a0);
            a1 = fmaf(arow[j + 1], wrow[j + 1], a1);
            a2 = fmaf(arow[j + 2], wrow[j + 2], a2);
            a3 = fmaf(arow[j + 3], wrow[j + 3], a3);
        }
        gi[out0 + p] = (a0 + a1) + (a2 + a3);
    }
}

// ---------------------------------------------------------------------------
// Kernel 4: sequential GRU — one wave/batch, explicit-register asm body.
//
// R6 evidence: 280-inst step ran at same 1300 cy as R3's 450-inst step ->
// ~700 cy stall unique to the readlane->SGPR->VALU pattern at distance
// 4-8 insts (deep-pipe interlock ~11 cy x 64 groups). Fix:
//   (1) rotate broadcasts through 4 SGPR PAIRS (s[10:17]) -> readlane
//       result consumed 4 groups (~15-20 insts, 30-40 cy) later.
//   (2) v_pk_fma_f32 (CDNA packed fp32): 3 pk-FMAs per j-PAIR with
//       s[even:odd] src0 -> matvec 256 -> 160 insts.
// Registers: v0 h | v1-v3 gi prefetch | v4:5 ar, v6:7 az, v8:9 an (pairs)
//   v10,v11,v18,v19 act temps | v12 gn_cur | v13-15 bias | v16/17 clamp
//   v20:21 gi ptr | v22:23 out ptr | v24-29 weight ptrs | v32-223 weights
// ---------------------------------------------------------------------------
#define LD4(D0, D3, B0, B1, OFF) \
  "global_load_dwordx4 v[" #D0 ":" #D3 "], v[" #B0 ":" #B1 "], off offset:" #OFF "\n\t"

// one j-pair group: 3 packed FMAs (acc.lo += h_even*w_even, acc.hi += h_odd*w_odd)
#define G(SP, W0,W1, Z0,Z1, N0,N1) \
  "v_pk_fma_f32 v[4:5], " SP ", v[" #W0 ":" #W1 "], v[4:5]\n\t" \
  "v_pk_fma_f32 v[6:7], " SP ", v[" #Z0 ":" #Z1 "], v[6:7]\n\t" \
  "v_pk_fma_f32 v[8:9], " SP ", v[" #N0 ":" #N1 "], v[8:9]\n\t"

// refill one SGPR pair for use 4 groups later
#define R2(Sa, La, Sb, Lb) \
  "v_readlane_b32 " Sa ", v0, " #La "\n\t" \
  "v_readlane_b32 " Sb ", v0, " #Lb "\n\t"

__global__
__attribute__((amdgpu_flat_work_group_size(64, 64)))
void k_gru(
    const float* __restrict__ gi, const float* __restrict__ Whh,
    const float* __restrict__ bhh, float* __restrict__ out)
{
    const int lane = threadIdx.x;     // 0..63
    const int b    = blockIdx.x;      // 0..7

    const float br = bhh[lane];
    const float bz = bhh[lane + 64];
    const float bn = bhh[lane + 128];

    const float* gib  = gi  + (size_t)b * 512 * 192;
    float*       outb = out + (size_t)b * 512 * 64;

    asm volatile(
        // ---- setup: weight base addresses (Whh + lane*256B; +16KB; +32KB)
        "v_lshlrev_b32 v30, 8, %[lane]\n\t"
        "v_mov_b32 v25, %[whi]\n\t"
        "v_add_co_u32 v24, vcc, %[wlo], v30\n\t"
        "v_addc_co_u32 v25, vcc, v25, 0, vcc\n\t"
        "v_add_co_u32 v26, vcc, 0x4000, v24\n\t"
        "v_mov_b32 v27, v25\n\t"
        "v_addc_co_u32 v27, vcc, v27, 0, vcc\n\t"
        "v_add_co_u32 v28, vcc, 0x8000, v24\n\t"
        "v_mov_b32 v29, v25\n\t"
        "v_addc_co_u32 v29, vcc, v29, 0, vcc\n\t"
        // ---- stage W_hh rows: wr->v32..95, wz->v96..159, wn->v160..223
        LD4( 32, 35,24,25,  0) LD4( 36, 39,24,25, 16) LD4( 40, 43,24,25, 32) LD4( 44, 47,24,25, 48)
        LD4( 48, 51,24,25, 64) LD4( 52, 55,24,25, 80) LD4( 56, 59,24,25, 96) LD4( 60, 63,24,25,112)
        LD4( 64, 67,24,25,128) LD4( 68, 71,24,25,144) LD4( 72, 75,24,25,160) LD4( 76, 79,24,25,176)
        LD4( 80, 83,24,25,192) LD4( 84, 87,24,25,208) LD4( 88, 91,24,25,224) LD4( 92, 95,24,25,240)
        LD4( 96, 99,26,27,  0) LD4(100,103,26,27, 16) LD4(104,107,26,27, 32) LD4(108,111,26,27, 48)
        LD4(112,115,26,27, 64) LD4(116,119,26,27, 80) LD4(120,123,26,27, 96) LD4(124,127,26,27,112)
        LD4(128,131,26,27,128) LD4(132,135,26,27,144) LD4(136,139,26,27,160) LD4(140,143,26,27,176)
        LD4(144,147,26,27,192) LD4(148,151,26,27,208) LD4(152,155,26,27,224) LD4(156,159,26,27,240)
        LD4(160,163,28,29,  0) LD4(164,167,28,29, 16) LD4(168,171,28,29, 32) LD4(172,175,28,29, 48)
        LD4(176,179,28,29, 64) LD4(180,183,28,29, 80) LD4(184,187,28,29, 96) LD4(188,191,28,29,112)
        LD4(192,195,28,29,128) LD4(196,199,28,29,144) LD4(200,203,28,29,160) LD4(204,207,28,29,176)
        LD4(208,211,28,29,192) LD4(212,215,28,29,208) LD4(216,219,28,29,224) LD4(220,223,28,29,240)
        // ---- gi / out pointers (+ lane*4)
        "v_lshlrev_b32 v30, 2, %[lane]\n\t"
        "v_mov_b32 v21, %[ghi]\n\t"
        "v_add_co_u32 v20, vcc, %[glo], v30\n\t"
        "v_addc_co_u32 v21, vcc, v21, 0, vcc\n\t"
        "v_mov_b32 v23, %[ohi]\n\t"
        "v_add_co_u32 v22, vcc, %[olo], v30\n\t"
        "v_addc_co_u32 v23, vcc, v23, 0, vcc\n\t"
        // ---- constants / state
        "v_mov_b32 v13, %[br]\n\t"
        "v_mov_b32 v14, %[bz]\n\t"
        "v_mov_b32 v15, %[bn]\n\t"
        "v_mov_b32 v16, 0x41700000\n\t"   // +15.0
        "v_mov_b32 v17, 0xc1700000\n\t"   // -15.0
        "v_mov_b32 v0, 0\n\t"             // h = 0
        // ---- preload gi[0]
        "global_load_dword v1, v[20:21], off\n\t"
        "global_load_dword v2, v[20:21], off offset:256\n\t"
        "global_load_dword v3, v[20:21], off offset:512\n\t"
        "s_mov_b32 s31, 0x200\n\t"
        "s_waitcnt vmcnt(0)\n\t"
        // ================= main loop: 512 steps =================
        "L_gru_%=:\n\t"
        "s_waitcnt vmcnt(1)\n\t"          // 3 gi loads done; store may fly
        // initial broadcast fill: h0..h7 -> s10..s17 (consumed >=14 insts later)
        R2("s10", 0, "s11", 1)
        R2("s12", 2, "s13", 3)
        R2("s14", 4, "s15", 5)
        R2("s16", 6, "s17", 7)
        // acc init (pairs): lo = bias+gi, hi = 0
        "v_add_f32 v4, v13, v1\n\t"
        "v_mov_b32 v5, 0\n\t"
        "v_add_f32 v6, v14, v2\n\t"
        "v_mov_b32 v7, 0\n\t"
        "v_mov_b32 v8, v15\n\t"
        "v_mov_b32 v9, 0\n\t"
        "v_mov_b32 v12, v3\n\t"           // gn_cur
        // advance gi ptr (clamped on last iter -> no OOB prefetch)
        "s_cmp_gt_u32 s31, 1\n\t"
        "s_cselect_b32 s8, 0x300, 0\n\t"
        "v_add_co_u32 v20, vcc, s8, v20\n\t"
        "v_addc_co_u32 v21, vcc, v21, 0, vcc\n\t"
        "global_load_dword v1, v[20:21], off\n\t"
        "global_load_dword v2, v[20:21], off offset:256\n\t"
        "global_load_dword v3, v[20:21], off offset:512\n\t"
        // ---- matvec: 32 j-pair groups, 4-pair SGPR rotation
        G("s[10:11]", 32,33,  96,97, 160,161) R2("s10",  8, "s11",  9)
        G("s[12:13]", 34,35,  98,99, 162,163) R2("s12", 10, "s13", 11)
        G("s[14:15]", 36,37, 100,101,164,165) R2("s14", 12, "s15", 13)
        G("s[16:17]", 38,39, 102,103,166,167) R2("s16", 14, "s17", 15)
        G("s[10:11]", 40,41, 104,105,168,169) R2("s10", 16, "s11", 17)
        G("s[12:13]", 42,43, 106,107,170,171) R2("s12", 18, "s13", 19)
        G("s[14:15]", 44,45, 108,109,172,173) R2("s14", 20, "s15", 21)
        G("s[16:17]", 46,47, 110,111,174,175) R2("s16", 22, "s17", 23)
        G("s[10:11]", 48,49, 112,113,176,177) R2("s10", 24, "s11", 25)
        G("s[12:13]", 50,51, 114,115,178,179) R2("s12", 26, "s13", 27)
        G("s[14:15]", 52,53, 116,117,180,181) R2("s14", 28, "s15", 29)
        G("s[16:17]", 54,55, 118,119,182,183) R2("s16", 30, "s17", 31)
        G("s[10:11]", 56,57, 120,121,184,185) R2("s10", 32, "s11", 33)
        G("s[12:13]", 58,59, 122,123,186,187) R2("s12", 34, "s13", 35)
        G("s[14:15]", 60,61, 124,125,188,189) R2("s14", 36, "s15", 37)
        G("s[16:17]", 62,63, 126,127,190,191) R2("s16", 38, "s17", 39)
        G("s[10:11]", 64,65, 128,129,192,193) R2("s10", 40, "s11", 41)
        G("s[12:13]", 66,67, 130,131,194,195) R2("s12", 42, "s13", 43)
        G("s[14:15]", 68,69, 132,133,196,197) R2("s14", 44, "s15", 45)
        G("s[16:17]", 70,71, 134,135,198,199) R2("s16", 46, "s17", 47)
        G("s[10:11]", 72,73, 136,137,200,201) R2("s10", 48, "s11", 49)
        G("s[12:13]", 74,75, 138,139,202,203) R2("s12", 50, "s13", 51)
        G("s[14:15]", 76,77, 140,141,204,205) R2("s14", 52, "s15", 53)
        G("s[16:17]", 78,79, 142,143,206,207) R2("s16", 54, "s17", 55)
        G("s[10:11]", 80,81, 144,145,208,209) R2("s10", 56, "s11", 57)
        G("s[12:13]", 82,83, 146,147,210,211) R2("s12", 58, "s13", 59)
        G("s[14:15]", 84,85, 148,149,212,213) R2("s14", 60, "s15", 61)
        G("s[16:17]", 86,87, 150,151,214,215) R2("s16", 62, "s17", 63)
        G("s[10:11]", 88,89, 152,153,216,217)
        G("s[12:13]", 90,91, 154,155,218,219)
        G("s[14:15]", 92,93, 156,157,220,221)
        G("s[16:17]", 94,95, 158,159,222,223)
        // ---- horizontal add of pair accumulators
        "v_add_f32 v4, v4, v5\n\t"        // ar
        "v_add_f32 v6, v6, v7\n\t"        // az
        "v_add_f32 v8, v8, v9\n\t"        // hn
        // ---- activations: r=sig(ar), z=sig(az), n=tanh(gn + r*hn)
        "v_mul_f32 v10, 0xbfb8aa3b, v4\n\t"   // -ar*log2e
        "v_mul_f32 v11, 0xbfb8aa3b, v6\n\t"
        "v_exp_f32 v10, v10\n\t"
        "v_exp_f32 v11, v11\n\t"
        "v_add_f32 v10, 1.0, v10\n\t"
        "v_add_f32 v11, 1.0, v11\n\t"
        "v_rcp_f32 v10, v10\n\t"              // r
        "v_rcp_f32 v11, v11\n\t"              // z
        "v_fmac_f32 v12, v10, v8\n\t"         // npre = gn + r*hn
        "v_med3_f32 v12, v12, v17, v16\n\t"   // clamp +-15
        "v_mul_f32 v18, 0x4038aa3b, v12\n\t"  // 2*log2e*npre
        "v_exp_f32 v18, v18\n\t"              // e2
        "s_nop 0\n\t"
        "v_add_f32 v19, 1.0, v18\n\t"
        "v_add_f32 v18, -1.0, v18\n\t"
        "v_rcp_f32 v19, v19\n\t"
        "s_nop 0\n\t"
        "v_mul_f32 v18, v18, v19\n\t"         // n = (e2-1)/(e2+1)
        "v_sub_f32 v10, v0, v18\n\t"          // h - n
        "v_fma_f32 v0, v11, v10, v18\n\t"     // h = z*(h-n)+n
        "global_store_dword v[22:23], v0, off\n\t"
        "v_add_co_u32 v22, vcc, 0x100, v22\n\t"
        "v_addc_co_u32 v23, vcc, v23, 0, vcc\n\t"
        "s_sub_u32 s31, s31, 1\n\t"
        "s_cmp_lg_u32 s31, 0\n\t"
        "s_cbranch_scc1 L_gru_%=\n\t"
        "s_waitcnt vmcnt(0)\n\t"
        :
        : [lane]"v"(lane), [br]"v"(br), [bz]"v"(bz), [bn]"v"(bn),
          [glo]"s"((unsigned)(unsigned long long)gib),
          [ghi]"s"((unsigned)((unsigned long long)gib >> 32)),
          [olo]"s"((unsigned)(unsigned long long)outb),
          [ohi]"s"((unsigned)((unsigned long long)outb >> 32)),
          [wlo]"s"((unsigned)(unsigned long long)Whh),
          [whi]"s"((unsigned)((unsigned long long)Whh >> 32))
        : "memory", "vcc", "scc", "s8", "s10", "s11", "s12", "s13", "s14", "s15", "s16", "s17", "s31",
          "v0","v1","v2","v3","v4","v5","v6","v7","v8","v9","v10","v11","v12","v13","v14","v15",
          "v16","v17","v18","v19","v20","v21","v22","v23","v24","v25","v26","v27","v28","v29","v30",
          "v32","v33","v34","v35","v36","v37","v38","v39","v40","v41","v42","v43","v44","v45","v46","v47",
          "v48","v49","v50","v51","v52","v53","v54","v55","v56","v57","v58","v59","v60","v61","v62","v63",
          "v64","v65","v66","v67","v68","v69","v70","v71","v72","v73","v74","v75","v76","v77","v78","v79",
          "v80","v81","v82","v83","v84","v85","v86","v87","v88","v89","v90","v91","v92","v93","v94","v95",
          "v96","v97","v98","v99","v100","v101","v102","v103","v104","v105","v106","v107","v108","v109","v110","v111",
          "v112","v113","v114","v115","v116","v117","v118","v119","v120","v121","v122","v123","v124","v125","v126","v127",
          "v128","v129","v130","v131","v132","v133","v134","v135","v136","v137","v138","v139","v140","v141","v142","v143",
          "v144","v145","v146","v147","v148","v149","v150","v151","v152","v153","v154","v155","v156","v157","v158","v159",
          "v160","v161","v162","v163","v164","v165","v166","v167","v168","v169","v170","v171","v172","v173","v174","v175",
          "v176","v177","v178","v179","v180","v181","v182","v183","v184","v185","v186","v187","v188","v189","v190","v191",
          "v192","v193","v194","v195","v196","v197","v198","v199","v200","v201","v202","v203","v204","v205","v206","v207",
          "v208","v209","v210","v211","v212","v213","v214","v215","v216","v217","v218","v219","v220","v221","v222","v223"
    );
}

// ---------------------------------------------------------------------------
extern "C" void kernel_launch(void* const* d_in, const int* in_sizes, int n_in,
                              void* d_out, int out_size, void* d_ws, size_t ws_size,
                              hipStream_t stream)
{
    const float* ts   = (const float*)d_in[0];
    const float* val  = (const float*)d_in[1];
    const int*   mark = (const int*)  d_in[2];
    const float* npm  = (const float*)d_in[3];
    const float* Wl   = (const float*)d_in[4];
    const float* bl   = (const float*)d_in[5];
    const float* Wp   = (const float*)d_in[6];
    const float* bp   = (const float*)d_in[7];
    const float* Wq   = (const float*)d_in[8];
    const float* bq   = (const float*)d_in[9];
    const float* Wk   = (const float*)d_in[10];
    const float* bk   = (const float*)d_in[11];
    const float* Wo   = (const float*)d_in[12];
    const float* bo   = (const float*)d_in[13];
    const float* Wih  = (const float*)d_in[14];
    const float* Whh  = (const float*)d_in[15];
    const float* bih  = (const float*)d_in[16];
    const float* bhh  = (const float*)d_in[17];

    float* ws    = (float*)d_ws;
    float* qmat  = ws;                 // 131072
    float* kmatT = ws + 131072;        // 131072
    float* att   = ws + 262144;        // 262144
    float* gi    = ws + 524288;        // 786432
    float* out   = (float*)d_out;

    k_embed<<<16, 256, 0, stream>>>(ts, Wl, bl, Wp, bp, Wq, bq, Wk, bk, qmat, kmatT);
    k_attn<<<dim3(32, 8), 256, 0, stream>>>(qmat, kmatT, val, mark, npm, Wo, bo, att);
    k_gi<<<256, 256, 0, stream>>>(att, Wih, bih, gi);
    k_gru<<<8, 64, 0, stream>>>(gi, Whh, bhh, out);
}